// Round 4
// baseline (357.676 us; speedup 1.0000x reference)
//
#include <hip/hip_runtime.h>
#include <hip/hip_bf16.h>

// Flash attention fwd, 1 head, B=64, S=1024, D=256.
// Inputs/outputs fp32 (per reference); compute in bf16 MFMA, fp32 accum.
// Dual-dtype insurance kept as ONE kernel with a block-uniform branch.
//
// R4: LDS arithmetic-intensity attack. R3 was still DS-pipe bound (~66%
// DS-busy by count model; MFMA 14/VALU 29/HBM 23 all idle). Each wave read
// the FULL K and V tiles (64 b128) to produce only 16 q-rows. Now each wave
// produces 32 q-rows (BQ=128, 4 waves, 256 thr): the same 64 B-frag reads
// feed 128 MFMAs (bfr/vf shared across two m-tiles), and staging, vs-build,
// and barriers halve per output. Per-CU DS cycles ~halve.
//  - VGPR: acc 128 + qf 64 + temps ~250; __launch_bounds__(256,2) = 256
//    budget (R2 lesson: never exceed the waves-per-EU reg budget).
//  - ps (per-wave private) reused mt0 then mt1: write0/read0/write1/read1,
//    ordered by per-wave in-order DS. LDS stays 75776 B -> 2 blocks/CU.
//  - grid (batch, qtile): id = batch + 64*qtile -> a batch's 8 blocks share
//    one XCD's L2 for KV.
// Carried from R3: DPP softmax reductions (no DS), vs dword-pair build,
// defer-rescale, KPAD=264, vs slot rotation ((d>>1)+kc)&7.

#define NB   64
#define NQ   1024
#define NKV  1024
#define DM   256
#define BQ   128    // q rows per block (4 waves x 32)
#define BK   64     // kv rows per tile
#define KPAD 264    // ks row stride (elems): 528B
#define PPAD 72     // ps row stride (elems): 144B, 16B-aligned
#define LOG2E   1.4426950408889634f
#define SCL     (0.0625f * LOG2E)   // fold scale=256^-0.5 into exp2 arg
#define NEG_BIG (-1e30f)            // finite "-inf"
#define THRU    30.0f               // defer threshold: P <= 2^(30*SCL) ~ 6.5

typedef __attribute__((ext_vector_type(8))) short  bf16x8;   // 8 bf16 = 4 VGPRs
typedef __attribute__((ext_vector_type(4))) float  floatx4;

__device__ __forceinline__ ushort f2bf(float f) {
  __hip_bfloat16 h = __float2bfloat16(f);
  return *(ushort*)&h;
}

// DPP lane-move within 16-lane rows (VALU pipe, no DS).
template <int CTRL>
__device__ __forceinline__ float dpp_mov(float x) {
  return __int_as_float(__builtin_amdgcn_update_dpp(
      0, __float_as_int(x), CTRL, 0xF, 0xF, false));
}
__device__ __forceinline__ float red16_max(float x) {
  x = fmaxf(x, dpp_mov<0xB1>(x));    // quad_perm xor1
  x = fmaxf(x, dpp_mov<0x4E>(x));    // quad_perm xor2
  x = fmaxf(x, dpp_mov<0x124>(x));   // row_ror:4
  x = fmaxf(x, dpp_mov<0x128>(x));   // row_ror:8
  return x;
}
__device__ __forceinline__ float red16_sum(float x) {
  x += dpp_mov<0xB1>(x);
  x += dpp_mov<0x4E>(x);
  x += dpp_mov<0x124>(x);
  x += dpp_mov<0x128>(x);
  return x;
}

// vs granule address (elems): granule = 8 consecutive kv of one d.
__device__ __forceinline__ int vsoff(int d, int kc) {
  return ((d >> 3) << 9) + ((d & 7) << 6) + ((((d >> 1) + kc) & 7) << 3);
}

// flag=1: data is bf16; flag=0: data is fp32.
__global__ void detect_dtype(const unsigned int* __restrict__ q,
                             int* __restrict__ flag) {
  __shared__ int cnt;
  if (threadIdx.x == 0) cnt = 0;
  __syncthreads();
  unsigned int w = q[(size_t)threadIdx.x * 32003u];
  unsigned int e = (w >> 7) & 0xFFu;
  int good = (e >= 96u && e < 160u) ? 1 : 0;
  atomicAdd(&cnt, good);
  __syncthreads();
  if (threadIdx.x == 0) flag[0] = (cnt > 192) ? 1 : 0;
}

template <bool IS_BF16>
__device__ __forceinline__ void attn_body(
    const void* __restrict__ qv, const void* __restrict__ kvv,
    void* __restrict__ outv, ushort* ks, ushort* vs, ushort* ps)
{
  const int tid   = threadIdx.x;
  const int wave  = tid >> 6;
  const int lane  = tid & 63;
  const int quad  = lane >> 4;
  const int l16   = lane & 15;
  const int batch = blockIdx.x;       // id%8 == batch%8 -> same-XCD KV share
  const int q0    = blockIdx.y * BQ + wave * 32;

  // Q fragments, A-layout: qf[mt][kb][j] = Q[m = mt*16 + l16][k = kb*32 + quad*8 + j]
  bf16x8 qf[2][8];
  if constexpr (IS_BF16) {
#pragma unroll
    for (int mt = 0; mt < 2; ++mt) {
      const ushort* qp = (const ushort*)qv +
          ((size_t)(batch * NQ + q0 + mt * 16 + l16)) * DM + quad * 8;
#pragma unroll
      for (int kb = 0; kb < 8; ++kb)
        qf[mt][kb] = *(const bf16x8*)(qp + kb * 32);
    }
  } else {
#pragma unroll
    for (int mt = 0; mt < 2; ++mt) {
      const float* qp = (const float*)qv +
          ((size_t)(batch * NQ + q0 + mt * 16 + l16)) * DM + quad * 8;
#pragma unroll
      for (int kb = 0; kb < 8; ++kb) {
        float4 f0 = *(const float4*)(qp + kb * 32);
        float4 f1 = *(const float4*)(qp + kb * 32 + 4);
        bf16x8 o; ushort* op = (ushort*)&o;
        op[0]=f2bf(f0.x); op[1]=f2bf(f0.y); op[2]=f2bf(f0.z); op[3]=f2bf(f0.w);
        op[4]=f2bf(f1.x); op[5]=f2bf(f1.y); op[6]=f2bf(f1.z); op[7]=f2bf(f1.w);
        qf[mt][kb] = o;
      }
    }
  }

  floatx4 acc[2][16];     // O acc: acc[mt][nt][r] = O[mt*16+quad*4+r][nt*16+l16]
#pragma unroll
  for (int mt = 0; mt < 2; ++mt)
#pragma unroll
    for (int i = 0; i < 16; ++i) acc[mt][i] = (floatx4){0.f, 0.f, 0.f, 0.f};
  float m_i[2][4], l_i[2][4];
#pragma unroll
  for (int mt = 0; mt < 2; ++mt)
#pragma unroll
    for (int r = 0; r < 4; ++r) { m_i[mt][r] = NEG_BIG; l_i[mt][r] = 0.f; }

  // PV read bases (loop-invariant)
  const int vbase = ((l16 >> 3) << 9) + ((l16 & 7) << 6);
  const int sl0 = ((quad     + (l16 >> 1)) & 7) << 3;   // kf=0 : kc = quad
  const int sl1 = ((quad + 4 + (l16 >> 1)) & 7) << 3;   // kf=1 : kc = quad+4

  ushort* pw = ps + wave * 16 * PPAD;

  for (int kt = 0; kt < NKV / BK; ++kt) {
    __syncthreads();  // protect ks/vs from previous iteration's readers
    // ---- stage kv tile 64x256 into LDS as bf16 (row-major, KPAD) ----
    if constexpr (IS_BF16) {
      const ushort* src = (const ushort*)kvv + ((size_t)batch * NKV + kt * BK) * DM;
#pragma unroll
      for (int i = 0; i < 8; ++i) {
        int v = tid + i * 256;
        int r = v >> 5;
        int c = (v & 31) << 3;
        *(bf16x8*)&ks[r * KPAD + c] = *(const bf16x8*)&src[r * DM + c];
      }
    } else {
      const float* src = (const float*)kvv + ((size_t)batch * NKV + kt * BK) * DM;
#pragma unroll
      for (int i = 0; i < 8; ++i) {
        int v = tid + i * 256;
        int r = v >> 5;
        int c = (v & 31) << 3;
        const float* sp = src + r * DM + c;
        float4 f0 = *(const float4*)(sp);
        float4 f1 = *(const float4*)(sp + 4);
        bf16x8 o; ushort* op = (ushort*)&o;
        op[0]=f2bf(f0.x); op[1]=f2bf(f0.y); op[2]=f2bf(f0.z); op[3]=f2bf(f0.w);
        op[4]=f2bf(f1.x); op[5]=f2bf(f1.y); op[6]=f2bf(f1.z); op[7]=f2bf(f1.w);
        *(bf16x8*)&ks[r * KPAD + c] = o;
      }
    }
    __syncthreads();

    // ---- S = Q @ K^T (unscaled): 32x64 per wave; bfr shared across mt ----
    floatx4 s[2][4];
#pragma unroll
    for (int mt = 0; mt < 2; ++mt)
#pragma unroll
      for (int nt = 0; nt < 4; ++nt) s[mt][nt] = (floatx4){0.f, 0.f, 0.f, 0.f};
#pragma unroll
    for (int nt = 0; nt < 4; ++nt) {
#pragma unroll
      for (int kb = 0; kb < 8; ++kb) {
        bf16x8 bfr = *(const bf16x8*)&ks[(nt * 16 + l16) * KPAD + kb * 32 + quad * 8];
        s[0][nt] = __builtin_amdgcn_mfma_f32_16x16x32_bf16(qf[0][kb], bfr, s[0][nt], 0, 0, 0);
        s[1][nt] = __builtin_amdgcn_mfma_f32_16x16x32_bf16(qf[1][kb], bfr, s[1][nt], 0, 0, 0);
      }
    }

    // ---- build vs: thread owns d-pair (d0,d0+1) x 4 kv-octets ----
    {
      const int d0 = (tid & 127) << 1;
      const int o0 = tid >> 7;            // 0 or 1
#pragma unroll
      for (int t = 0; t < 4; ++t) {
        const int oct = o0 + t * 2;       // kv-octet 0..7
        const ushort* kp = ks + (oct << 3) * KPAD + d0;
        uint x0 = *(const uint*)(kp);
        uint y0 = *(const uint*)(kp + KPAD);
        uint x1 = *(const uint*)(kp + 2 * KPAD);
        uint y1 = *(const uint*)(kp + 3 * KPAD);
        uint x2 = *(const uint*)(kp + 4 * KPAD);
        uint y2 = *(const uint*)(kp + 5 * KPAD);
        uint x3 = *(const uint*)(kp + 6 * KPAD);
        uint y3 = *(const uint*)(kp + 7 * KPAD);
        uint4 glo, ghi;
        glo.x = (x0 & 0xFFFFu) | (y0 << 16);
        glo.y = (x1 & 0xFFFFu) | (y1 << 16);
        glo.z = (x2 & 0xFFFFu) | (y2 << 16);
        glo.w = (x3 & 0xFFFFu) | (y3 << 16);
        ghi.x = (x0 >> 16) | (y0 & 0xFFFF0000u);
        ghi.y = (x1 >> 16) | (y1 & 0xFFFF0000u);
        ghi.z = (x2 >> 16) | (y2 & 0xFFFF0000u);
        ghi.w = (x3 >> 16) | (y3 & 0xFFFF0000u);
        *(uint4*)&vs[vsoff(d0,     oct)] = glo;
        *(uint4*)&vs[vsoff(d0 + 1, oct)] = ghi;
      }
    }

    // ---- online softmax (DPP, deferred rescale over both m-tiles) ----
    float mx[2][4];
#pragma unroll
    for (int mt = 0; mt < 2; ++mt)
#pragma unroll
      for (int r = 0; r < 4; ++r) {
        float m0 = fmaxf(fmaxf(s[mt][0][r], s[mt][1][r]),
                         fmaxf(s[mt][2][r], s[mt][3][r]));
        mx[mt][r] = red16_max(m0);
      }
    float grow = NEG_BIG;
#pragma unroll
    for (int mt = 0; mt < 2; ++mt)
#pragma unroll
      for (int r = 0; r < 4; ++r) grow = fmaxf(grow, mx[mt][r] - m_i[mt][r]);
    if (__any(grow > THRU)) {
#pragma unroll
      for (int mt = 0; mt < 2; ++mt)
#pragma unroll
        for (int r = 0; r < 4; ++r) {
          float mnew  = fmaxf(m_i[mt][r], mx[mt][r]);
          float alpha = exp2f(fmaxf((m_i[mt][r] - mnew) * SCL, -126.f));
          l_i[mt][r] *= alpha;
          m_i[mt][r]  = mnew;
#pragma unroll
          for (int nt = 0; nt < 16; ++nt) acc[mt][nt][r] *= alpha;
        }
    }

    // ---- P = exp(S-m): write straight to ps; per-wave ps reused mt0,mt1 ----
    bf16x8 pf[2][2];
#pragma unroll
    for (int mt = 0; mt < 2; ++mt) {
#pragma unroll
      for (int r = 0; r < 4; ++r) {
        float rs = 0.f;
#pragma unroll
        for (int nt = 0; nt < 4; ++nt) {
          float p = exp2f((s[mt][nt][r] - m_i[mt][r]) * SCL);
          pw[(quad * 4 + r) * PPAD + nt * 16 + l16] = f2bf(p);
          rs += p;
        }
        l_i[mt][r] += red16_sum(rs);
      }
      // per-wave in-order DS: these reads complete before mt1's writes land
#pragma unroll
      for (int kf = 0; kf < 2; ++kf)
        pf[mt][kf] = *(const bf16x8*)&pw[l16 * PPAD + kf * 32 + quad * 8];
    }
    __syncthreads();   // vs fully built by all waves

    // ---- O += P @ V : V-frags shared across both m-tiles ----
#pragma unroll
    for (int nt = 0; nt < 16; ++nt) {
      const ushort* vb = vs + (nt << 10) + vbase;
      bf16x8 v0 = *(const bf16x8*)(vb + sl0);
      acc[0][nt] = __builtin_amdgcn_mfma_f32_16x16x32_bf16(pf[0][0], v0, acc[0][nt], 0, 0, 0);
      acc[1][nt] = __builtin_amdgcn_mfma_f32_16x16x32_bf16(pf[1][0], v0, acc[1][nt], 0, 0, 0);
      bf16x8 v1 = *(const bf16x8*)(vb + sl1);
      acc[0][nt] = __builtin_amdgcn_mfma_f32_16x16x32_bf16(pf[0][1], v1, acc[0][nt], 0, 0, 0);
      acc[1][nt] = __builtin_amdgcn_mfma_f32_16x16x32_bf16(pf[1][1], v1, acc[1][nt], 0, 0, 0);
    }
  }

  // ---- epilogue: O / l, store in the REFERENCE dtype ----
#pragma unroll
  for (int mt = 0; mt < 2; ++mt)
#pragma unroll
    for (int r = 0; r < 4; ++r) l_i[mt][r] = 1.f / l_i[mt][r];
  if constexpr (IS_BF16) {
#pragma unroll
    for (int mt = 0; mt < 2; ++mt) {
      ushort* ob = (ushort*)outv +
          ((size_t)(batch * NQ + q0 + mt * 16 + quad * 4)) * DM + l16;
#pragma unroll
      for (int nt = 0; nt < 16; ++nt)
#pragma unroll
        for (int r = 0; r < 4; ++r)
          ob[(size_t)r * DM + nt * 16] = f2bf(acc[mt][nt][r] * l_i[mt][r]);
    }
  } else {
#pragma unroll
    for (int mt = 0; mt < 2; ++mt) {
      float* ob = (float*)outv +
          ((size_t)(batch * NQ + q0 + mt * 16 + quad * 4)) * DM + l16;
#pragma unroll
      for (int nt = 0; nt < 16; ++nt)
#pragma unroll
        for (int r = 0; r < 4; ++r)
          ob[(size_t)r * DM + nt * 16] = acc[mt][nt][r] * l_i[mt][r];
    }
  }
}

__global__ __launch_bounds__(256, 2) void attn_fwd(
    const void* __restrict__ qv, const void* __restrict__ kvv,
    void* __restrict__ outv, const int* __restrict__ flag)
{
  __shared__ ushort ks[BK * KPAD];           // kv tile, row-major padded (~33KB)
  __shared__ ushort vs[BK * DM];             // granule-transposed V copy (32KB)
  __shared__ ushort ps[4 * 16 * PPAD];       // per-wave P staging (~9KB)

  if (flag[0] != 0)  // block-uniform: barrier-safe
    attn_body<true >(qv, kvv, outv, ks, vs, ps);
  else
    attn_body<false>(qv, kvv, outv, ks, vs, ps);
}

extern "C" void kernel_launch(void* const* d_in, const int* in_sizes, int n_in,
                              void* d_out, int out_size, void* d_ws, size_t ws_size,
                              hipStream_t stream) {
  const void* q  = d_in[0];
  const void* kv = d_in[1];
  int* flag      = (int*)d_ws;

  detect_dtype<<<dim3(1), dim3(256), 0, stream>>>((const unsigned int*)q, flag);

  dim3 grid(NB, NQ / BQ);   // x=batch: a batch's 8 q-tile blocks share an XCD
  attn_fwd<<<grid, dim3(256), 0, stream>>>(q, kv, d_out, flag);
}